// Round 7
// baseline (198.559 us; speedup 1.0000x reference)
//
#include <hip/hip_runtime.h>
#include <math.h>

#define DIN   128
#define DOUT  64
#define NHEAD 4
#define HD    16

typedef __attribute__((ext_vector_type(8))) short bf16x8;
typedef __attribute__((ext_vector_type(8))) unsigned short u16x8;
typedef __attribute__((ext_vector_type(4))) float f32x4;

__device__ __forceinline__ unsigned short f2bf(float f) {
    union { float f; unsigned u; } v; v.f = f;
    unsigned r = v.u + 0x7FFF + ((v.u >> 16) & 1);   // round-to-nearest-even
    return (unsigned short)(r >> 16);
}
__device__ __forceinline__ float bf2f(unsigned short s) {
    union { unsigned u; float f; } v; v.u = ((unsigned)s) << 16; return v.f;
}

// ---------------- prep: W^T bf16 [192][128] + zero degi ---------------------
__global__ __launch_bounds__(256)
void k_prep(const float* __restrict__ Ws, const float* __restrict__ Wd,
            const float* __restrict__ Wl, short* __restrict__ wT,
            int* __restrict__ degi, int N) {
    const int idx = blockIdx.x * 256 + threadIdx.x;
    if (idx < 192 * 128) {
        const int n = idx >> 7, k = idx & 127;
        float v;
        if (n < 64)       v = Ws[k * DOUT + n];
        else if (n < 128) v = Wd[k * DOUT + (n - 64)];
        else              v = Wl[k * DOUT + (n - 128)];
        wT[idx] = (short)f2bf(v);
    }
    if (idx < N) degi[idx] = 0;
}

// ---------------- node projections via MFMA (1 wave = 16 nodes) -------------
// packed_bf[node][p*8+t] : t<4 -> xs head t pos p ; t>=4 -> h head (t-4) pos p
// xd_perm[node][p*4+head]
__global__ __launch_bounds__(64)
void k_node_proj(const float* __restrict__ x, const short* __restrict__ wT,
                 const float* __restrict__ bs, const float* __restrict__ bd,
                 const float* __restrict__ bl, const float* __restrict__ Wa,
                 unsigned short* __restrict__ packed_bf, // [N][128] shorts
                 float* __restrict__ xd_perm,            // [N][64]
                 float* __restrict__ alpha_s, float* __restrict__ alpha_d,
                 float* __restrict__ h_out, int N) {
    __shared__ short xs[16 * 136];
    const int lane = threadIdx.x;
    const int lam = lane & 15, g = lane >> 4;
    const int n0 = blockIdx.x * 16;

    {
        const int r = lane >> 2, c0 = (lane & 3) * 32;
        const int nn = n0 + r;
#pragma unroll
        for (int j = 0; j < 8; ++j) {
            float4 v = make_float4(0.f, 0.f, 0.f, 0.f);
            if (nn < N) v = ((const float4*)x)[(size_t)nn * 32 + (c0 >> 2) + j];
            short4 h4;
            h4.x = (short)f2bf(v.x); h4.y = (short)f2bf(v.y);
            h4.z = (short)f2bf(v.z); h4.w = (short)f2bf(v.w);
            *(short4*)&xs[r * 136 + c0 + j * 4] = h4;
        }
    }
    __syncthreads();

    bf16x8 afr[4];
#pragma unroll
    for (int ks = 0; ks < 4; ++ks)
        afr[ks] = *(const bf16x8*)&xs[lam * 136 + ks * 32 + g * 8];

    f32x4 acc[12];
#pragma unroll
    for (int c = 0; c < 12; ++c) acc[c] = (f32x4){0.f, 0.f, 0.f, 0.f};

#pragma unroll
    for (int c = 0; c < 12; ++c) {
#pragma unroll
        for (int ks = 0; ks < 4; ++ks) {
            const bf16x8 b = *(const bf16x8*)&wT[(c * 16 + lam) * 128 + ks * 32 + g * 8];
            acc[c] = __builtin_amdgcn_mfma_f32_16x16x32_bf16(afr[ks], b, acc[c], 0, 0, 0);
        }
    }

    float bsv[4], bdv[4], blv[4];
#pragma unroll
    for (int c = 0; c < 4; ++c) {
        bsv[c] = bs[c * 16 + lam];
        bdv[c] = bd[c * 16 + lam];
        blv[c] = bl[c * 16 + lam];
    }
    const float waS = Wa[lam], waD = Wa[16 + lam];

#pragma unroll
    for (int i = 0; i < 4; ++i) {
        const int node = n0 + g * 4 + i;
        float xsv[4], xdv[4], hv[4];
#pragma unroll
        for (int c = 0; c < 4; ++c) {
            xsv[c] = acc[c][i]     + bsv[c];
            xdv[c] = acc[4 + c][i] + bdv[c];
            hv[c]  = acc[8 + c][i] + blv[c];
        }
        float p0 = hv[0] * waS, p1 = hv[1] * waS, p2 = hv[2] * waS, p3 = hv[3] * waS;
        float q0 = hv[0] * waD, q1 = hv[1] * waD, q2 = hv[2] * waD, q3 = hv[3] * waD;
#pragma unroll
        for (int off = 1; off < 16; off <<= 1) {
            p0 += __shfl_xor(p0, off); p1 += __shfl_xor(p1, off);
            p2 += __shfl_xor(p2, off); p3 += __shfl_xor(p3, off);
            q0 += __shfl_xor(q0, off); q1 += __shfl_xor(q1, off);
            q2 += __shfl_xor(q2, off); q3 += __shfl_xor(q3, off);
        }
        if (node < N) {
            u16x8 pk;
#pragma unroll
            for (int c = 0; c < 4; ++c) {
                pk[c]     = f2bf(xsv[c]);
                pk[4 + c] = f2bf(hv[c]);
            }
            *(u16x8*)&packed_bf[(size_t)node * 128 + lam * 8] = pk;
            *(f32x4*)&xd_perm[(size_t)node * DOUT + lam * 4] =
                (f32x4){xdv[0], xdv[1], xdv[2], xdv[3]};
#pragma unroll
            for (int c = 0; c < 4; ++c)
                h_out[(size_t)node * DOUT + c * 16 + lam] = hv[c];
            if (lam == 0) {
                *(f32x4*)&alpha_s[(size_t)node * NHEAD] = (f32x4){p0, p1, p2, p3};
                *(f32x4*)&alpha_d[(size_t)node * NHEAD] = (f32x4){q0, q1, q2, q3};
            }
        }
    }
}

// ---------------- CSR build ------------------------------------------------
__global__ __launch_bounds__(256)
void k_hist(const int* __restrict__ dst, int* __restrict__ degi,
            int* __restrict__ rank, int E) {
    int e = blockIdx.x * 256 + threadIdx.x;
    if (e < E) rank[e] = atomicAdd(&degi[dst[e]], 1);
}

__global__ __launch_bounds__(1024)
void k_scan_block(const int* __restrict__ degi, int* __restrict__ excl,
                  int* __restrict__ bsum, int N) {
    __shared__ int wsum[16];
    const int tid = threadIdx.x, lane = tid & 63, wid = tid >> 6;
    const int i = blockIdx.x * 1024 + tid;
    int v = (i < N) ? degi[i] : 0;
    int incl = v;
#pragma unroll
    for (int off = 1; off < 64; off <<= 1) {
        int t = __shfl_up(incl, off);
        if (lane >= off) incl += t;
    }
    if (lane == 63) wsum[wid] = incl;
    __syncthreads();
    if (tid < 16) {
        int t = wsum[tid];
#pragma unroll
        for (int off = 1; off < 16; off <<= 1) {
            int u = __shfl_up(t, off);
            if (tid >= off) t += u;
        }
        wsum[tid] = t;
    }
    __syncthreads();
    const int base = (wid > 0) ? wsum[wid - 1] : 0;
    if (i < N) excl[i] = incl - v + base;
    if (tid == 1023) bsum[blockIdx.x] = wsum[15];
}

__global__ __launch_bounds__(1024)
void k_scan_bsum(const int* __restrict__ bsum, int* __restrict__ boff,
                 int* __restrict__ total, int nb) {
    __shared__ int wsum[16];
    const int tid = threadIdx.x, lane = tid & 63, wid = tid >> 6;
    int v = (tid < nb) ? bsum[tid] : 0;
    int incl = v;
#pragma unroll
    for (int off = 1; off < 64; off <<= 1) {
        int t = __shfl_up(incl, off);
        if (lane >= off) incl += t;
    }
    if (lane == 63) wsum[wid] = incl;
    __syncthreads();
    if (tid < 16) {
        int t = wsum[tid];
#pragma unroll
        for (int off = 1; off < 16; off <<= 1) {
            int u = __shfl_up(t, off);
            if (tid >= off) t += u;
        }
        wsum[tid] = t;
    }
    __syncthreads();
    const int base = (wid > 0) ? wsum[wid - 1] : 0;
    if (tid < nb) boff[tid] = incl - v + base;
    if (tid == 1023) *total = wsum[15];
}

__global__ __launch_bounds__(256)
void k_scatter(const int* __restrict__ src, const int* __restrict__ dst,
               const int* __restrict__ rp_raw, const int* __restrict__ boff,
               const int* __restrict__ rank, int* __restrict__ srcs_sorted, int E) {
    int e = blockIdx.x * 256 + threadIdx.x;
    if (e >= E) return;
    const int d = dst[e];
    srcs_sorted[rp_raw[d] + boff[d >> 10] + rank[e]] = src[e];
}

// ---------------- fused per-dst aggregation: MFMA scores, 16 edges/iter -----
// Wave handles 1 node. Lane (g,lam): edge = lam, packed-row chunk j*32+g*8
// (pos p=j*4+g, slots t: 0-3 xs heads, 4-7 h heads).
// Score MFMA: A[m=head][k]=wa (block-diag, const), B[k][n=edge]=er,
// C = alpha_s+alpha_d+ba  ->  D[m=head][n=edge] = full pre-leaky score.
__global__ __launch_bounds__(128)
void k_aggregate(const int* __restrict__ rp_raw, const int* __restrict__ boff,
                 const int* __restrict__ total, const int* __restrict__ srcs,
                 const unsigned short* __restrict__ packed_bf, // [N][128]
                 const float* __restrict__ xd_perm,            // [N][64]
                 const float* __restrict__ alpha_s, const float* __restrict__ alpha_d,
                 const float* __restrict__ Wa, const float* __restrict__ ba,
                 float* __restrict__ edge_s, float* __restrict__ out, int N) {
    const int lane = threadIdx.x & 63;
    const int n = blockIdx.x * 2 + (threadIdx.x >> 6);
    if (n >= N) return;
    const int g = lane >> 4, lam = lane & 15;

    const int start = rp_raw[n] + boff[n >> 10];
    const int end = (n + 1 < N) ? (rp_raw[n + 1] + boff[(n + 1) >> 10]) : *total;
    const int deg = end - start;

    // loop-invariants
    const float ba0 = ba[0];
    const f32x4 ad4 = *(const f32x4*)&alpha_d[(size_t)n * NHEAD];
    f32x4 xd[4];
#pragma unroll
    for (int j = 0; j < 4; ++j)
        xd[j] = *(const f32x4*)&xd_perm[(size_t)n * DOUT + (j * 4 + g) * 4];

    bf16x8 af[4];
#pragma unroll
    for (int j = 0; j < 4; ++j) {
        union { float f; unsigned u; } wv; wv.f = Wa[32 + j * 4 + g];
        const short wb = (short)(wv.u >> 16);
#pragma unroll
        for (int i = 0; i < 8; ++i)
            af[j][i] = (i < 4 && i == lam) ? wb : (short)0;
    }
    const float adb0 = ad4[0] + ba0, adb1 = ad4[1] + ba0,
                adb2 = ad4[2] + ba0, adb3 = ad4[3] + ba0;

    float es[16], op[16];
#pragma unroll
    for (int r = 0; r < 16; ++r) { es[r] = 0.f; op[r] = 0.f; }
    float s0 = 0.f, s1 = 0.f, s2 = 0.f, s3 = 0.f;

    const int niter = (deg + 15) >> 4;
    for (int it = 0; it < niter; ++it) {
        const int e = start + it * 16 + lam;
        const float vm = (e < end) ? 1.f : 0.f;
        const int sn = srcs[min(e, end - 1)];
        const size_t rowb = (size_t)sn * 128;
        union { u16x8 v; unsigned d[4]; } pk[4];
#pragma unroll
        for (int j = 0; j < 4; ++j)
            pk[j].v = *(const u16x8*)&packed_bf[rowb + j * 32 + g * 8];
        const f32x4 as4 = *(const f32x4*)&alpha_s[(size_t)sn * NHEAD];

        f32x4 acc;
        acc[0] = (g == 0) ? as4[0] + adb0 : 0.f;
        acc[1] = (g == 0) ? as4[1] + adb1 : 0.f;
        acc[2] = (g == 0) ? as4[2] + adb2 : 0.f;
        acc[3] = (g == 0) ? as4[3] + adb3 : 0.f;

#pragma unroll
        for (int j = 0; j < 4; ++j) {
            float er[4];
#pragma unroll
            for (int t = 0; t < 4; ++t) {
                const float xv = bf2f(pk[j].v[t]) + xd[j][t];
                const float tt = __expf(2.f * xv);
                er[t] = fmaf(-2.f, __builtin_amdgcn_rcpf(tt + 1.f), 1.f);
                es[j * 4 + t] = fmaf(er[t], vm, es[j * 4 + t]);
            }
            union { bf16x8 v; unsigned d[4]; } bf;
            union { float f; unsigned u; } e0, e1, e2, e3;
            e0.f = er[0]; e1.f = er[1]; e2.f = er[2]; e3.f = er[3];
            bf.d[0] = (e0.u >> 16) | (e1.u & 0xFFFF0000u);
            bf.d[1] = (e2.u >> 16) | (e3.u & 0xFFFF0000u);
            bf.d[2] = pk[j].d[2];
            bf.d[3] = pk[j].d[3];
            acc = __builtin_amdgcn_mfma_f32_16x16x32_bf16(af[j], bf.v, acc, 0, 0, 0);
        }

        // scores -> exp weights (rows 0-3 live in g==0 lanes)
        float w0, w1, w2, w3;
        {
            float sc0 = acc[0], sc1 = acc[1], sc2 = acc[2], sc3 = acc[3];
            sc0 = fmaxf(sc0, 0.01f * sc0); sc1 = fmaxf(sc1, 0.01f * sc1);
            sc2 = fmaxf(sc2, 0.01f * sc2); sc3 = fmaxf(sc3, 0.01f * sc3);
            w0 = __expf(sc0) * vm; w1 = __expf(sc1) * vm;
            w2 = __expf(sc2) * vm; w3 = __expf(sc3) * vm;
        }
        s0 += w0; s1 += w1; s2 += w2; s3 += w3;

        const float wh0 = __shfl(w0, lam);
        const float wh1 = __shfl(w1, lam);
        const float wh2 = __shfl(w2, lam);
        const float wh3 = __shfl(w3, lam);

#pragma unroll
        for (int j = 0; j < 4; ++j) {
            op[j * 4 + 0] = fmaf(wh0, bf2f(pk[j].v[4]), op[j * 4 + 0]);
            op[j * 4 + 1] = fmaf(wh1, bf2f(pk[j].v[5]), op[j * 4 + 1]);
            op[j * 4 + 2] = fmaf(wh2, bf2f(pk[j].v[6]), op[j * 4 + 2]);
            op[j * 4 + 3] = fmaf(wh3, bf2f(pk[j].v[7]), op[j * 4 + 3]);
        }
    }

    // reduce over lam (g-groups independent)
#pragma unroll
    for (int off = 1; off < 16; off <<= 1) {
#pragma unroll
        for (int r = 0; r < 16; ++r) {
            es[r] += __shfl_xor(es[r], off);
            op[r] += __shfl_xor(op[r], off);
        }
        s0 += __shfl_xor(s0, off); s1 += __shfl_xor(s1, off);
        s2 += __shfl_xor(s2, off); s3 += __shfl_xor(s3, off);
    }
    // s finals live in g==0 lanes; broadcast from lane index lam (g=0)
    const float sb0 = __shfl(s0, lam), sb1 = __shfl(s1, lam),
                sb2 = __shfl(s2, lam), sb3 = __shfl(s3, lam);
    const int t = lam >> 2, j = lam & 3;
    const float sg_ = (t == 0) ? sb0 : (t == 1) ? sb1 : (t == 2) ? sb2 : sb3;
    const int r_sel = j * 4 + t;
    float ov = op[0], ev = es[0];
#pragma unroll
    for (int r = 1; r < 16; ++r) {
        ov = (r_sel == r) ? op[r] : ov;
        ev = (r_sel == r) ? es[r] : ev;
    }
    const int dim = t * 16 + j * 4 + g;
    const size_t od = (size_t)n * DOUT + dim;
    out[od]    = ov * __builtin_amdgcn_rcpf(fmaxf(sg_, 1e-38f));
    edge_s[od] = ev * __builtin_amdgcn_rcpf(fmaxf((float)deg, 1.0f));
}

extern "C" void kernel_launch(void* const* d_in, const int* in_sizes, int n_in,
                              void* d_out, int out_size, void* d_ws, size_t ws_size,
                              hipStream_t stream) {
    const float* x  = (const float*)d_in[0];
    const int*   src= (const int*)  d_in[1];
    const int*   dst= (const int*)  d_in[2];
    const float* Ws = (const float*)d_in[3];
    const float* bs = (const float*)d_in[4];
    const float* Wd = (const float*)d_in[5];
    const float* bd = (const float*)d_in[6];
    const float* Wl = (const float*)d_in[7];
    const float* bl = (const float*)d_in[8];
    const float* Wa = (const float*)d_in[9];
    const float* ba = (const float*)d_in[10];

    const int N = in_sizes[0] / DIN;
    const int E = in_sizes[1];
    const int NB = (N + 1023) / 1024;

    float* out_f = (float*)d_out;
    float* edge_s_out = out_f;                        // chunk 0: [N,64]
    float* out_attn   = out_f + (size_t)N * DOUT;     // chunk 1: [N,64]
    float* h_out      = out_f + 2 * (size_t)N * DOUT; // chunk 2: [N,64]

    char* ws = (char*)d_ws;
    size_t o = 0;
    unsigned short* packed_bf = (unsigned short*)(ws + o); o += (size_t)N * 128 * 2;
    float* xd_perm = (float*)(ws + o); o += (size_t)N * DOUT * 4;
    float* alpha_s = (float*)(ws + o); o += (size_t)N * NHEAD * 4;
    float* alpha_d = (float*)(ws + o); o += (size_t)N * NHEAD * 4;
    int*   degi    = (int*)  (ws + o); o += (size_t)N * 4;
    int*   rp_raw  = (int*)  (ws + o); o += (size_t)(N + 1) * 4;
    int*   rank    = (int*)  (ws + o); o += (size_t)E * 4;
    int*   srcs    = (int*)  (ws + o); o += (size_t)E * 4;
    int*   bsum    = (int*)  (ws + o); o += (size_t)NB * 4;
    int*   boff    = (int*)  (ws + o); o += (size_t)NB * 4;
    int*   total   = (int*)  (ws + o); o += 64;
    short* wT      = (short*)(ws + o); o += (size_t)192 * 128 * 2;

    const int prep_n = (N > 192 * 128) ? N : 192 * 128;
    k_prep<<<(prep_n + 255) / 256, 256, 0, stream>>>(Ws, Wd, Wl, wT, degi, N);

    k_node_proj<<<(N + 15) / 16, 64, 0, stream>>>(x, wT, bs, bd, bl, Wa,
                                                  packed_bf, xd_perm, alpha_s, alpha_d,
                                                  h_out, N);

    k_hist<<<(E + 255) / 256, 256, 0, stream>>>(dst, degi, rank, E);

    k_scan_block<<<NB, 1024, 0, stream>>>(degi, rp_raw, bsum, N);
    k_scan_bsum<<<1, 1024, 0, stream>>>(bsum, boff, total, NB);

    k_scatter<<<(E + 255) / 256, 256, 0, stream>>>(src, dst, rp_raw, boff, rank, srcs, E);

    k_aggregate<<<(N + 1) / 2, 128, 0, stream>>>(rp_raw, boff, total, srcs,
                                                 packed_bf, xd_perm,
                                                 alpha_s, alpha_d, Wa, ba,
                                                 edge_s_out, out_attn, N);
}

// Round 8
// 160.684 us; speedup vs baseline: 1.2357x; 1.2357x over previous
//
#include <hip/hip_runtime.h>
#include <math.h>

#define DIN   128
#define DOUT  64
#define NHEAD 4
#define HD    16

typedef __attribute__((ext_vector_type(8))) short bf16x8;
typedef __attribute__((ext_vector_type(8))) unsigned short u16x8;
typedef __attribute__((ext_vector_type(4))) float f32x4;

__device__ __forceinline__ unsigned short f2bf(float f) {
    union { float f; unsigned u; } v; v.f = f;
    unsigned r = v.u + 0x7FFF + ((v.u >> 16) & 1);   // round-to-nearest-even
    return (unsigned short)(r >> 16);
}
__device__ __forceinline__ float bf2f(unsigned short s) {
    union { unsigned u; float f; } v; v.u = ((unsigned)s) << 16; return v.f;
}

// ---------------- prep: W^T bf16 [192][128] + zero degi ---------------------
__global__ __launch_bounds__(256)
void k_prep(const float* __restrict__ Ws, const float* __restrict__ Wd,
            const float* __restrict__ Wl, short* __restrict__ wT,
            int* __restrict__ degi, int N) {
    const int idx = blockIdx.x * 256 + threadIdx.x;
    if (idx < 192 * 128) {
        const int n = idx >> 7, k = idx & 127;
        float v;
        if (n < 64)       v = Ws[k * DOUT + n];
        else if (n < 128) v = Wd[k * DOUT + (n - 64)];
        else              v = Wl[k * DOUT + (n - 128)];
        wT[idx] = (short)f2bf(v);
    }
    if (idx < N) degi[idx] = 0;
}

// ---------------- node projections via MFMA (1 wave = 16 nodes) -------------
// packed_bf[node][p*8+t] : t<4 -> xs head t pos p ; t>=4 -> h head (t-4) pos p
// xd_perm[node][p*4+head]
__global__ __launch_bounds__(64)
void k_node_proj(const float* __restrict__ x, const short* __restrict__ wT,
                 const float* __restrict__ bs, const float* __restrict__ bd,
                 const float* __restrict__ bl, const float* __restrict__ Wa,
                 unsigned short* __restrict__ packed_bf, // [N][128] shorts
                 float* __restrict__ xd_perm,            // [N][64]
                 float* __restrict__ alpha_s, float* __restrict__ alpha_d,
                 float* __restrict__ h_out, int N) {
    __shared__ short xs[16 * 136];
    const int lane = threadIdx.x;
    const int lam = lane & 15, g = lane >> 4;
    const int n0 = blockIdx.x * 16;

    {
        const int r = lane >> 2, c0 = (lane & 3) * 32;
        const int nn = n0 + r;
#pragma unroll
        for (int j = 0; j < 8; ++j) {
            float4 v = make_float4(0.f, 0.f, 0.f, 0.f);
            if (nn < N) v = ((const float4*)x)[(size_t)nn * 32 + (c0 >> 2) + j];
            short4 h4;
            h4.x = (short)f2bf(v.x); h4.y = (short)f2bf(v.y);
            h4.z = (short)f2bf(v.z); h4.w = (short)f2bf(v.w);
            *(short4*)&xs[r * 136 + c0 + j * 4] = h4;
        }
    }
    __syncthreads();

    bf16x8 afr[4];
#pragma unroll
    for (int ks = 0; ks < 4; ++ks)
        afr[ks] = *(const bf16x8*)&xs[lam * 136 + ks * 32 + g * 8];

    f32x4 acc[12];
#pragma unroll
    for (int c = 0; c < 12; ++c) acc[c] = (f32x4){0.f, 0.f, 0.f, 0.f};

#pragma unroll
    for (int c = 0; c < 12; ++c) {
#pragma unroll
        for (int ks = 0; ks < 4; ++ks) {
            const bf16x8 b = *(const bf16x8*)&wT[(c * 16 + lam) * 128 + ks * 32 + g * 8];
            acc[c] = __builtin_amdgcn_mfma_f32_16x16x32_bf16(afr[ks], b, acc[c], 0, 0, 0);
        }
    }

    float bsv[4], bdv[4], blv[4];
#pragma unroll
    for (int c = 0; c < 4; ++c) {
        bsv[c] = bs[c * 16 + lam];
        bdv[c] = bd[c * 16 + lam];
        blv[c] = bl[c * 16 + lam];
    }
    const float waS = Wa[lam], waD = Wa[16 + lam];

#pragma unroll
    for (int i = 0; i < 4; ++i) {
        const int node = n0 + g * 4 + i;
        float xsv[4], xdv[4], hv[4];
#pragma unroll
        for (int c = 0; c < 4; ++c) {
            xsv[c] = acc[c][i]     + bsv[c];
            xdv[c] = acc[4 + c][i] + bdv[c];
            hv[c]  = acc[8 + c][i] + blv[c];
        }
        float p0 = hv[0] * waS, p1 = hv[1] * waS, p2 = hv[2] * waS, p3 = hv[3] * waS;
        float q0 = hv[0] * waD, q1 = hv[1] * waD, q2 = hv[2] * waD, q3 = hv[3] * waD;
#pragma unroll
        for (int off = 1; off < 16; off <<= 1) {
            p0 += __shfl_xor(p0, off); p1 += __shfl_xor(p1, off);
            p2 += __shfl_xor(p2, off); p3 += __shfl_xor(p3, off);
            q0 += __shfl_xor(q0, off); q1 += __shfl_xor(q1, off);
            q2 += __shfl_xor(q2, off); q3 += __shfl_xor(q3, off);
        }
        if (node < N) {
            u16x8 pk;
#pragma unroll
            for (int c = 0; c < 4; ++c) {
                pk[c]     = f2bf(xsv[c]);
                pk[4 + c] = f2bf(hv[c]);
            }
            *(u16x8*)&packed_bf[(size_t)node * 128 + lam * 8] = pk;
            *(f32x4*)&xd_perm[(size_t)node * DOUT + lam * 4] =
                (f32x4){xdv[0], xdv[1], xdv[2], xdv[3]};
#pragma unroll
            for (int c = 0; c < 4; ++c)
                h_out[(size_t)node * DOUT + c * 16 + lam] = hv[c];
            if (lam == 0) {
                *(f32x4*)&alpha_s[(size_t)node * NHEAD] = (f32x4){p0, p1, p2, p3};
                *(f32x4*)&alpha_d[(size_t)node * NHEAD] = (f32x4){q0, q1, q2, q3};
            }
        }
    }
}

// ---------------- CSR build ------------------------------------------------
__global__ __launch_bounds__(256)
void k_hist(const int* __restrict__ dst, int* __restrict__ degi,
            int* __restrict__ rank, int E) {
    int e = blockIdx.x * 256 + threadIdx.x;
    if (e < E) rank[e] = atomicAdd(&degi[dst[e]], 1);
}

__global__ __launch_bounds__(1024)
void k_scan_block(const int* __restrict__ degi, int* __restrict__ excl,
                  int* __restrict__ bsum, int N) {
    __shared__ int wsum[16];
    const int tid = threadIdx.x, lane = tid & 63, wid = tid >> 6;
    const int i = blockIdx.x * 1024 + tid;
    int v = (i < N) ? degi[i] : 0;
    int incl = v;
#pragma unroll
    for (int off = 1; off < 64; off <<= 1) {
        int t = __shfl_up(incl, off);
        if (lane >= off) incl += t;
    }
    if (lane == 63) wsum[wid] = incl;
    __syncthreads();
    if (tid < 16) {
        int t = wsum[tid];
#pragma unroll
        for (int off = 1; off < 16; off <<= 1) {
            int u = __shfl_up(t, off);
            if (tid >= off) t += u;
        }
        wsum[tid] = t;
    }
    __syncthreads();
    const int base = (wid > 0) ? wsum[wid - 1] : 0;
    if (i < N) excl[i] = incl - v + base;
    if (tid == 1023) bsum[blockIdx.x] = wsum[15];
}

__global__ __launch_bounds__(1024)
void k_scan_bsum(const int* __restrict__ bsum, int* __restrict__ boff,
                 int* __restrict__ total, int nb) {
    __shared__ int wsum[16];
    const int tid = threadIdx.x, lane = tid & 63, wid = tid >> 6;
    int v = (tid < nb) ? bsum[tid] : 0;
    int incl = v;
#pragma unroll
    for (int off = 1; off < 64; off <<= 1) {
        int t = __shfl_up(incl, off);
        if (lane >= off) incl += t;
    }
    if (lane == 63) wsum[wid] = incl;
    __syncthreads();
    if (tid < 16) {
        int t = wsum[tid];
#pragma unroll
        for (int off = 1; off < 16; off <<= 1) {
            int u = __shfl_up(t, off);
            if (tid >= off) t += u;
        }
        wsum[tid] = t;
    }
    __syncthreads();
    const int base = (wid > 0) ? wsum[wid - 1] : 0;
    if (tid < nb) boff[tid] = incl - v + base;
    if (tid == 1023) *total = wsum[15];
}

__global__ __launch_bounds__(256)
void k_scatter(const int* __restrict__ src, const int* __restrict__ dst,
               const int* __restrict__ rp_raw, const int* __restrict__ boff,
               const int* __restrict__ rank, int* __restrict__ srcs_sorted, int E) {
    int e = blockIdx.x * 256 + threadIdx.x;
    if (e >= E) return;
    const int d = dst[e];
    srcs_sorted[rp_raw[d] + boff[d >> 10] + rank[e]] = src[e];
}

// ---------------- fused per-dst aggregation: 1 node/wave, 4 edges/iter ------
// 16 lanes per edge (group g); lane lam owns heads 0..3 at position lam,
// loaded as ONE 16B dwordx4 (4 bf16 xs + 4 bf16 h).  Prefetch distance 2.
__global__ __launch_bounds__(256)
void k_aggregate(const int* __restrict__ rp_raw, const int* __restrict__ boff,
                 const int* __restrict__ total, const int* __restrict__ srcs,
                 const unsigned short* __restrict__ packed_bf, // [N][128]
                 const float* __restrict__ xd_perm,            // [N][64]
                 const float* __restrict__ alpha_s, const float* __restrict__ alpha_d,
                 const float* __restrict__ Wa, const float* __restrict__ ba,
                 float* __restrict__ edge_s, float* __restrict__ out, int N) {
    const int lane = threadIdx.x & 63;
    const int n = blockIdx.x * 4 + (threadIdx.x >> 6);
    if (n >= N) return;
    const int g = lane >> 4, lam = lane & 15;

    const int start = rp_raw[n] + boff[n >> 10];
    const int end = (n + 1 < N) ? (rp_raw[n + 1] + boff[(n + 1) >> 10]) : *total;
    const int deg = end - start;
    const int last = end - 1;

    const float4 xd4 = *(const float4*)&xd_perm[(size_t)n * DOUT + lam * 4];
    const float4 ad4 = *(const float4*)&alpha_d[(size_t)n * NHEAD];
    const float wa   = Wa[32 + lam];
    const float ba0  = ba[0];
    const float adb0 = ad4.x + ba0, adb1 = ad4.y + ba0,
                adb2 = ad4.z + ba0, adb3 = ad4.w + ba0;

    float es0=0.f,es1=0.f,es2=0.f,es3=0.f;
    float s0=0.f,s1=0.f,s2=0.f,s3=0.f;
    float o0=0.f,o1=0.f,o2=0.f,o3=0.f;

    const int niter = (deg + 3) >> 2;
    int e = start + g;

    // rotating 2-deep pipeline: P0 (compute next), P1 (in flight), load -> P1
    float vm0 = 0.f, vm1 = 0.f;
    u16x8 pk0 = (u16x8){0,0,0,0,0,0,0,0}, pk1 = pk0;
    float4 as0 = make_float4(0,0,0,0), as1 = as0;
    if (niter > 0) {
        vm0 = (e < end) ? 1.f : 0.f;
        const int sn = srcs[min(e, last)];
        pk0 = *(const u16x8*)&packed_bf[(size_t)sn * 128 + lam * 8];
        as0 = *(const float4*)&alpha_s[(size_t)sn * NHEAD];
        const int e1 = e + 4;
        vm1 = (e1 < end) ? 1.f : 0.f;
        const int sn1 = srcs[min(e1, last)];
        pk1 = *(const u16x8*)&packed_bf[(size_t)sn1 * 128 + lam * 8];
        as1 = *(const float4*)&alpha_s[(size_t)sn1 * NHEAD];
    }

    for (int it = 0; it < niter; ++it) {
        // issue prefetch for it+2
        float vmn = 0.f;
        u16x8 pkn = (u16x8){0,0,0,0,0,0,0,0};
        float4 asn = make_float4(0,0,0,0);
        const int e2 = e + 8;
        if (it + 2 < niter) {
            vmn = (e2 < end) ? 1.f : 0.f;
            const int sn = srcs[min(e2, last)];
            pkn = *(const u16x8*)&packed_bf[(size_t)sn * 128 + lam * 8];
            asn = *(const float4*)&alpha_s[(size_t)sn * NHEAD];
        }

        // compute with P0
        const float t0 = __expf(2.f * (bf2f(pk0[0]) + xd4.x));
        const float t1 = __expf(2.f * (bf2f(pk0[1]) + xd4.y));
        const float t2 = __expf(2.f * (bf2f(pk0[2]) + xd4.z));
        const float t3 = __expf(2.f * (bf2f(pk0[3]) + xd4.w));
        const float er0 = fmaf(-2.f, __builtin_amdgcn_rcpf(t0 + 1.f), 1.f);
        const float er1 = fmaf(-2.f, __builtin_amdgcn_rcpf(t1 + 1.f), 1.f);
        const float er2 = fmaf(-2.f, __builtin_amdgcn_rcpf(t2 + 1.f), 1.f);
        const float er3 = fmaf(-2.f, __builtin_amdgcn_rcpf(t3 + 1.f), 1.f);
        es0 = fmaf(er0, vm0, es0); es1 = fmaf(er1, vm0, es1);
        es2 = fmaf(er2, vm0, es2); es3 = fmaf(er3, vm0, es3);

        float p0 = er0 * wa, p1 = er1 * wa, p2 = er2 * wa, p3 = er3 * wa;
#pragma unroll
        for (int off = 1; off < 16; off <<= 1) {
            p0 += __shfl_xor(p0, off); p1 += __shfl_xor(p1, off);
            p2 += __shfl_xor(p2, off); p3 += __shfl_xor(p3, off);
        }
        float a0 = as0.x + adb0 + p0;
        float a1 = as0.y + adb1 + p1;
        float a2 = as0.z + adb2 + p2;
        float a3 = as0.w + adb3 + p3;
        a0 = (a0 >= 0.f) ? a0 : 0.01f * a0;
        a1 = (a1 >= 0.f) ? a1 : 0.01f * a1;
        a2 = (a2 >= 0.f) ? a2 : 0.01f * a2;
        a3 = (a3 >= 0.f) ? a3 : 0.01f * a3;
        const float w0 = __expf(a0) * vm0;
        const float w1 = __expf(a1) * vm0;
        const float w2 = __expf(a2) * vm0;
        const float w3 = __expf(a3) * vm0;
        s0 += w0; s1 += w1; s2 += w2; s3 += w3;
        o0 = fmaf(w0, bf2f(pk0[4]), o0); o1 = fmaf(w1, bf2f(pk0[5]), o1);
        o2 = fmaf(w2, bf2f(pk0[6]), o2); o3 = fmaf(w3, bf2f(pk0[7]), o3);

        // rotate
        vm0 = vm1; pk0 = pk1; as0 = as1;
        vm1 = vmn; pk1 = pkn; as1 = asn;
        e += 4;
    }

#pragma unroll
    for (int off = 16; off < 64; off <<= 1) {
        es0 += __shfl_xor(es0, off); es1 += __shfl_xor(es1, off);
        es2 += __shfl_xor(es2, off); es3 += __shfl_xor(es3, off);
        s0  += __shfl_xor(s0,  off); s1  += __shfl_xor(s1,  off);
        s2  += __shfl_xor(s2,  off); s3  += __shfl_xor(s3,  off);
        o0  += __shfl_xor(o0,  off); o1  += __shfl_xor(o1,  off);
        o2  += __shfl_xor(o2,  off); o3  += __shfl_xor(o3,  off);
    }

    const float og  = (g == 0) ? o0  : (g == 1) ? o1  : (g == 2) ? o2  : o3;
    const float sg  = (g == 0) ? s0  : (g == 1) ? s1  : (g == 2) ? s2  : s3;
    const float eg  = (g == 0) ? es0 : (g == 1) ? es1 : (g == 2) ? es2 : es3;
    const size_t od = (size_t)n * DOUT + g * 16 + lam;
    out[od]    = og * __builtin_amdgcn_rcpf(fmaxf(sg, 1e-38f));
    edge_s[od] = eg * __builtin_amdgcn_rcpf(fmaxf((float)deg, 1.0f));
}

extern "C" void kernel_launch(void* const* d_in, const int* in_sizes, int n_in,
                              void* d_out, int out_size, void* d_ws, size_t ws_size,
                              hipStream_t stream) {
    const float* x  = (const float*)d_in[0];
    const int*   src= (const int*)  d_in[1];
    const int*   dst= (const int*)  d_in[2];
    const float* Ws = (const float*)d_in[3];
    const float* bs = (const float*)d_in[4];
    const float* Wd = (const float*)d_in[5];
    const float* bd = (const float*)d_in[6];
    const float* Wl = (const float*)d_in[7];
    const float* bl = (const float*)d_in[8];
    const float* Wa = (const float*)d_in[9];
    const float* ba = (const float*)d_in[10];

    const int N = in_sizes[0] / DIN;
    const int E = in_sizes[1];
    const int NB = (N + 1023) / 1024;

    float* out_f = (float*)d_out;
    float* edge_s_out = out_f;                        // chunk 0: [N,64]
    float* out_attn   = out_f + (size_t)N * DOUT;     // chunk 1: [N,64]
    float* h_out      = out_f + 2 * (size_t)N * DOUT; // chunk 2: [N,64]

    char* ws = (char*)d_ws;
    size_t o = 0;
    unsigned short* packed_bf = (unsigned short*)(ws + o); o += (size_t)N * 128 * 2;
    float* xd_perm = (float*)(ws + o); o += (size_t)N * DOUT * 4;
    float* alpha_s = (float*)(ws + o); o += (size_t)N * NHEAD * 4;
    float* alpha_d = (float*)(ws + o); o += (size_t)N * NHEAD * 4;
    int*   degi    = (int*)  (ws + o); o += (size_t)N * 4;
    int*   rp_raw  = (int*)  (ws + o); o += (size_t)(N + 1) * 4;
    int*   rank    = (int*)  (ws + o); o += (size_t)E * 4;
    int*   srcs    = (int*)  (ws + o); o += (size_t)E * 4;
    int*   bsum    = (int*)  (ws + o); o += (size_t)NB * 4;
    int*   boff    = (int*)  (ws + o); o += (size_t)NB * 4;
    int*   total   = (int*)  (ws + o); o += 64;
    short* wT      = (short*)(ws + o); o += (size_t)192 * 128 * 2;

    const int prep_n = (N > 192 * 128) ? N : 192 * 128;
    k_prep<<<(prep_n + 255) / 256, 256, 0, stream>>>(Ws, Wd, Wl, wT, degi, N);

    k_node_proj<<<(N + 15) / 16, 64, 0, stream>>>(x, wT, bs, bd, bl, Wa,
                                                  packed_bf, xd_perm, alpha_s, alpha_d,
                                                  h_out, N);

    k_hist<<<(E + 255) / 256, 256, 0, stream>>>(dst, degi, rank, E);

    k_scan_block<<<NB, 1024, 0, stream>>>(degi, rp_raw, bsum, N);
    k_scan_bsum<<<1, 1024, 0, stream>>>(bsum, boff, total, NB);

    k_scatter<<<(E + 255) / 256, 256, 0, stream>>>(src, dst, rp_raw, boff, rank, srcs, E);

    k_aggregate<<<(N + 3) / 4, 256, 0, stream>>>(rp_raw, boff, total, srcs,
                                                 packed_bf, xd_perm,
                                                 alpha_s, alpha_d, Wa, ba,
                                                 edge_s_out, out_attn, N);
}

// Round 9
// 137.802 us; speedup vs baseline: 1.4409x; 1.1660x over previous
//
#include <hip/hip_runtime.h>
#include <math.h>

#define DIN   128
#define DOUT  64
#define NHEAD 4
#define HD    16

typedef __attribute__((ext_vector_type(8))) short bf16x8;
typedef __attribute__((ext_vector_type(8))) unsigned short u16x8;
typedef __attribute__((ext_vector_type(4))) float f32x4;

__device__ __forceinline__ unsigned short f2bf(float f) {
    union { float f; unsigned u; } v; v.f = f;
    unsigned r = v.u + 0x7FFF + ((v.u >> 16) & 1);   // round-to-nearest-even
    return (unsigned short)(r >> 16);
}
__device__ __forceinline__ float bf2f(unsigned short s) {
    union { unsigned u; float f; } v; v.u = ((unsigned)s) << 16; return v.f;
}

// ---------------- prep: W^T bf16 [192][128] + zero degi ---------------------
__global__ __launch_bounds__(256)
void k_prep(const float* __restrict__ Ws, const float* __restrict__ Wd,
            const float* __restrict__ Wl, short* __restrict__ wT,
            int* __restrict__ degi, int N) {
    const int idx = blockIdx.x * 256 + threadIdx.x;
    if (idx < 192 * 128) {
        const int n = idx >> 7, k = idx & 127;
        float v;
        if (n < 64)       v = Ws[k * DOUT + n];
        else if (n < 128) v = Wd[k * DOUT + (n - 64)];
        else              v = Wl[k * DOUT + (n - 128)];
        wT[idx] = (short)f2bf(v);
    }
    if (idx < N) degi[idx] = 0;
}

// ---------------- node projections via MFMA (1 wave = 16 nodes) -------------
// packed_bf[node] : 16 chunks of 8 shorts. chunk cc = head*4+q holds
//   slots 0-3: xs dims head*16+q*4..+3 ; slots 4-7: h same dims.
// xd[node][64] row-major f32.
__global__ __launch_bounds__(64)
void k_node_proj(const float* __restrict__ x, const short* __restrict__ wT,
                 const float* __restrict__ bs, const float* __restrict__ bd,
                 const float* __restrict__ bl, const float* __restrict__ Wa,
                 unsigned short* __restrict__ packed_bf, // [N][128] shorts
                 float* __restrict__ xd,                 // [N][64] row-major
                 float* __restrict__ alpha_s, float* __restrict__ alpha_d,
                 float* __restrict__ h_out, int N) {
    __shared__ short xs[16 * 136];
    const int lane = threadIdx.x;
    const int lam = lane & 15, g = lane >> 4;
    const int n0 = blockIdx.x * 16;

    {
        const int r = lane >> 2, c0 = (lane & 3) * 32;
        const int nn = n0 + r;
#pragma unroll
        for (int j = 0; j < 8; ++j) {
            float4 v = make_float4(0.f, 0.f, 0.f, 0.f);
            if (nn < N) v = ((const float4*)x)[(size_t)nn * 32 + (c0 >> 2) + j];
            short4 h4;
            h4.x = (short)f2bf(v.x); h4.y = (short)f2bf(v.y);
            h4.z = (short)f2bf(v.z); h4.w = (short)f2bf(v.w);
            *(short4*)&xs[r * 136 + c0 + j * 4] = h4;
        }
    }
    __syncthreads();

    bf16x8 afr[4];
#pragma unroll
    for (int ks = 0; ks < 4; ++ks)
        afr[ks] = *(const bf16x8*)&xs[lam * 136 + ks * 32 + g * 8];

    f32x4 acc[12];
#pragma unroll
    for (int c = 0; c < 12; ++c) acc[c] = (f32x4){0.f, 0.f, 0.f, 0.f};

#pragma unroll
    for (int c = 0; c < 12; ++c) {
#pragma unroll
        for (int ks = 0; ks < 4; ++ks) {
            const bf16x8 b = *(const bf16x8*)&wT[(c * 16 + lam) * 128 + ks * 32 + g * 8];
            acc[c] = __builtin_amdgcn_mfma_f32_16x16x32_bf16(afr[ks], b, acc[c], 0, 0, 0);
        }
    }

    float bsv[4], bdv[4], blv[4];
#pragma unroll
    for (int c = 0; c < 4; ++c) {
        bsv[c] = bs[c * 16 + lam];
        bdv[c] = bd[c * 16 + lam];
        blv[c] = bl[c * 16 + lam];
    }
    const float waS = Wa[lam], waD = Wa[16 + lam];
    const int cc_base = (lam >> 2), t_sl = lam & 3;   // chunk sub-index / slot

#pragma unroll
    for (int i = 0; i < 4; ++i) {
        const int node = n0 + g * 4 + i;
        float xsv[4], xdv[4], hv[4];
#pragma unroll
        for (int c = 0; c < 4; ++c) {
            xsv[c] = acc[c][i]     + bsv[c];
            xdv[c] = acc[4 + c][i] + bdv[c];
            hv[c]  = acc[8 + c][i] + blv[c];
        }
        float p0 = hv[0] * waS, p1 = hv[1] * waS, p2 = hv[2] * waS, p3 = hv[3] * waS;
        float q0 = hv[0] * waD, q1 = hv[1] * waD, q2 = hv[2] * waD, q3 = hv[3] * waD;
#pragma unroll
        for (int off = 1; off < 16; off <<= 1) {
            p0 += __shfl_xor(p0, off); p1 += __shfl_xor(p1, off);
            p2 += __shfl_xor(p2, off); p3 += __shfl_xor(p3, off);
            q0 += __shfl_xor(q0, off); q1 += __shfl_xor(q1, off);
            q2 += __shfl_xor(q2, off); q3 += __shfl_xor(q3, off);
        }
        if (node < N) {
            const size_t rowb = (size_t)node * 128;
#pragma unroll
            for (int c = 0; c < 4; ++c) {
                const int cc = c * 4 + cc_base;      // head c, quad lam>>2
                packed_bf[rowb + cc * 8 + t_sl]     = f2bf(xsv[c]);
                packed_bf[rowb + cc * 8 + 4 + t_sl] = f2bf(hv[c]);
                xd   [(size_t)node * DOUT + c * 16 + lam] = xdv[c];
                h_out[(size_t)node * DOUT + c * 16 + lam] = hv[c];
            }
            if (lam == 0) {
                *(f32x4*)&alpha_s[(size_t)node * NHEAD] = (f32x4){p0, p1, p2, p3};
                *(f32x4*)&alpha_d[(size_t)node * NHEAD] = (f32x4){q0, q1, q2, q3};
            }
        }
    }
}

// ---------------- CSR build ------------------------------------------------
__global__ __launch_bounds__(256)
void k_hist(const int* __restrict__ dst, int* __restrict__ degi,
            int* __restrict__ rank, int E) {
    const int e0 = (blockIdx.x * 256 + threadIdx.x) * 4;
    if (e0 + 3 < E) {
        const int4 d = *(const int4*)&dst[e0];
        int4 r;
        r.x = atomicAdd(&degi[d.x], 1);
        r.y = atomicAdd(&degi[d.y], 1);
        r.z = atomicAdd(&degi[d.z], 1);
        r.w = atomicAdd(&degi[d.w], 1);
        *(int4*)&rank[e0] = r;
    } else {
        for (int e = e0; e < E; ++e) rank[e] = atomicAdd(&degi[dst[e]], 1);
    }
}

__global__ __launch_bounds__(1024)
void k_scan_block(const int* __restrict__ degi, int* __restrict__ excl,
                  int* __restrict__ bsum, int N) {
    __shared__ int wsum[16];
    const int tid = threadIdx.x, lane = tid & 63, wid = tid >> 6;
    const int i = blockIdx.x * 1024 + tid;
    int v = (i < N) ? degi[i] : 0;
    int incl = v;
#pragma unroll
    for (int off = 1; off < 64; off <<= 1) {
        int t = __shfl_up(incl, off);
        if (lane >= off) incl += t;
    }
    if (lane == 63) wsum[wid] = incl;
    __syncthreads();
    if (tid < 16) {
        int t = wsum[tid];
#pragma unroll
        for (int off = 1; off < 16; off <<= 1) {
            int u = __shfl_up(t, off);
            if (tid >= off) t += u;
        }
        wsum[tid] = t;
    }
    __syncthreads();
    const int base = (wid > 0) ? wsum[wid - 1] : 0;
    if (i < N) excl[i] = incl - v + base;
    if (tid == 1023) bsum[blockIdx.x] = wsum[15];
}

__global__ __launch_bounds__(1024)
void k_scan_bsum(const int* __restrict__ bsum, int* __restrict__ boff,
                 int* __restrict__ total, int nb) {
    __shared__ int wsum[16];
    const int tid = threadIdx.x, lane = tid & 63, wid = tid >> 6;
    int v = (tid < nb) ? bsum[tid] : 0;
    int incl = v;
#pragma unroll
    for (int off = 1; off < 64; off <<= 1) {
        int t = __shfl_up(incl, off);
        if (lane >= off) incl += t;
    }
    if (lane == 63) wsum[wid] = incl;
    __syncthreads();
    if (tid < 16) {
        int t = wsum[tid];
#pragma unroll
        for (int off = 1; off < 16; off <<= 1) {
            int u = __shfl_up(t, off);
            if (tid >= off) t += u;
        }
        wsum[tid] = t;
    }
    __syncthreads();
    const int base = (wid > 0) ? wsum[wid - 1] : 0;
    if (tid < nb) boff[tid] = incl - v + base;
    if (tid == 1023) *total = wsum[15];
}

__global__ __launch_bounds__(256)
void k_scatter(const int* __restrict__ src, const int* __restrict__ dst,
               const int* __restrict__ rp_raw, const int* __restrict__ boff,
               const int* __restrict__ rank, int* __restrict__ srcs_sorted, int E) {
    const int e0 = (blockIdx.x * 256 + threadIdx.x) * 4;
    if (e0 + 3 < E) {
        const int4 s = *(const int4*)&src[e0];
        const int4 d = *(const int4*)&dst[e0];
        const int4 r = *(const int4*)&rank[e0];
        srcs_sorted[rp_raw[d.x] + boff[d.x >> 10] + r.x] = s.x;
        srcs_sorted[rp_raw[d.y] + boff[d.y >> 10] + r.y] = s.y;
        srcs_sorted[rp_raw[d.z] + boff[d.z >> 10] + r.z] = s.z;
        srcs_sorted[rp_raw[d.w] + boff[d.w >> 10] + r.w] = s.w;
    } else {
        for (int e = e0; e < E; ++e) {
            const int d = dst[e];
            srcs_sorted[rp_raw[d] + boff[d >> 10] + rank[e]] = src[e];
        }
    }
}

// ---------------- fused per-dst aggregation: 1 node/wave, 4 edges/iter ------
// lane = (g=edge group, hd=lam>>2, q=lam&3); lane owns dims hd*16+q*4..+3.
// per edge-lane: one 16B packed chunk (4 xs + 4 h bf16), scalar alpha_s.
// score reduce: 4 in-lane FMA + xor1,xor2 (4-lane subgroup). Prefetch dist 2.
__global__ __launch_bounds__(256, 8)
void k_aggregate(const int* __restrict__ rp_raw, const int* __restrict__ boff,
                 const int* __restrict__ total, const int* __restrict__ srcs,
                 const unsigned short* __restrict__ packed_bf, // [N][128]
                 const float* __restrict__ xd,                 // [N][64]
                 const float* __restrict__ alpha_s, const float* __restrict__ alpha_d,
                 const float* __restrict__ Wa, const float* __restrict__ ba,
                 float* __restrict__ edge_s, float* __restrict__ out, int N) {
    const int lane = threadIdx.x & 63;
    const int n = blockIdx.x * 4 + (threadIdx.x >> 6);
    if (n >= N) return;
    const int g = lane >> 4, lam = lane & 15;
    const int hd = lam >> 2, q = lam & 3;

    const int start = rp_raw[n] + boff[n >> 10];
    const int end = (n + 1 < N) ? (rp_raw[n + 1] + boff[(n + 1) >> 10]) : *total;
    const int deg = end - start;
    const int last = end - 1;

    const float4 xd4 = *(const float4*)&xd[(size_t)n * DOUT + lam * 4];
    const float4 wa4 = *(const float4*)&Wa[32 + q * 4];
    const float adb  = alpha_d[n * NHEAD + hd] + ba[0];

    float es0=0.f,es1=0.f,es2=0.f,es3=0.f;
    float o0=0.f,o1=0.f,o2=0.f,o3=0.f;
    float s = 0.f;

    const int niter = (deg + 3) >> 2;
    int e = start + g;

    float vm0 = 0.f, vm1 = 0.f;
    u16x8 pk0 = (u16x8){0,0,0,0,0,0,0,0}, pk1 = pk0;
    float as0 = 0.f, as1 = 0.f;
    if (niter > 0) {
        vm0 = (e < end) ? 1.f : 0.f;
        const int sn = srcs[min(e, last)];
        pk0 = *(const u16x8*)&packed_bf[(size_t)sn * 128 + lam * 8];
        as0 = alpha_s[sn * NHEAD + hd];
        const int e1 = e + 4;
        vm1 = (e1 < end) ? 1.f : 0.f;
        const int sn1 = srcs[min(e1, last)];
        pk1 = *(const u16x8*)&packed_bf[(size_t)sn1 * 128 + lam * 8];
        as1 = alpha_s[sn1 * NHEAD + hd];
    }

    for (int it = 0; it < niter; ++it) {
        // prefetch it+2
        float vmn = 0.f, asn = 0.f;
        u16x8 pkn = (u16x8){0,0,0,0,0,0,0,0};
        const int e2 = e + 8;
        if (it + 2 < niter) {
            vmn = (e2 < end) ? 1.f : 0.f;
            const int sn = srcs[min(e2, last)];
            pkn = *(const u16x8*)&packed_bf[(size_t)sn * 128 + lam * 8];
            asn = alpha_s[sn * NHEAD + hd];
        }

        // er = tanh(xs + xd) for this lane's 4 dims
        const float t0 = __expf(2.f * (bf2f(pk0[0]) + xd4.x));
        const float t1 = __expf(2.f * (bf2f(pk0[1]) + xd4.y));
        const float t2 = __expf(2.f * (bf2f(pk0[2]) + xd4.z));
        const float t3 = __expf(2.f * (bf2f(pk0[3]) + xd4.w));
        const float er0 = fmaf(-2.f, __builtin_amdgcn_rcpf(t0 + 1.f), 1.f);
        const float er1 = fmaf(-2.f, __builtin_amdgcn_rcpf(t1 + 1.f), 1.f);
        const float er2 = fmaf(-2.f, __builtin_amdgcn_rcpf(t2 + 1.f), 1.f);
        const float er3 = fmaf(-2.f, __builtin_amdgcn_rcpf(t3 + 1.f), 1.f);
        es0 = fmaf(er0, vm0, es0); es1 = fmaf(er1, vm0, es1);
        es2 = fmaf(er2, vm0, es2); es3 = fmaf(er3, vm0, es3);

        // per-head score partial over this lane's 4 positions
        float p = er0 * wa4.x;
        p = fmaf(er1, wa4.y, p);
        p = fmaf(er2, wa4.z, p);
        p = fmaf(er3, wa4.w, p);
        p += __shfl_xor(p, 1);
        p += __shfl_xor(p, 2);

        float a = as0 + adb + p;
        a = (a >= 0.f) ? a : 0.01f * a;            // leaky relu
        const float w = __expf(a) * vm0;
        s += w;
        o0 = fmaf(w, bf2f(pk0[4]), o0); o1 = fmaf(w, bf2f(pk0[5]), o1);
        o2 = fmaf(w, bf2f(pk0[6]), o2); o3 = fmaf(w, bf2f(pk0[7]), o3);

        // rotate pipeline
        vm0 = vm1; pk0 = pk1; as0 = as1;
        vm1 = vmn; pk1 = pkn; as1 = asn;
        e += 4;
    }

    // reduce across the 4 edge groups
#pragma unroll
    for (int off = 16; off < 64; off <<= 1) {
        es0 += __shfl_xor(es0, off); es1 += __shfl_xor(es1, off);
        es2 += __shfl_xor(es2, off); es3 += __shfl_xor(es3, off);
        o0  += __shfl_xor(o0,  off); o1  += __shfl_xor(o1,  off);
        o2  += __shfl_xor(o2,  off); o3  += __shfl_xor(o3,  off);
        s   += __shfl_xor(s,   off);
    }

    if (g == 0) {
        const float inv_s = __builtin_amdgcn_rcpf(fmaxf(s, 1e-38f));
        const float inv_d = __builtin_amdgcn_rcpf(fmaxf((float)deg, 1.0f));
        const size_t od = (size_t)n * DOUT + lam * 4;
        *(f32x4*)&out[od]    = (f32x4){o0 * inv_s, o1 * inv_s, o2 * inv_s, o3 * inv_s};
        *(f32x4*)&edge_s[od] = (f32x4){es0 * inv_d, es1 * inv_d, es2 * inv_d, es3 * inv_d};
    }
}

extern "C" void kernel_launch(void* const* d_in, const int* in_sizes, int n_in,
                              void* d_out, int out_size, void* d_ws, size_t ws_size,
                              hipStream_t stream) {
    const float* x  = (const float*)d_in[0];
    const int*   src= (const int*)  d_in[1];
    const int*   dst= (const int*)  d_in[2];
    const float* Ws = (const float*)d_in[3];
    const float* bs = (const float*)d_in[4];
    const float* Wd = (const float*)d_in[5];
    const float* bd = (const float*)d_in[6];
    const float* Wl = (const float*)d_in[7];
    const float* bl = (const float*)d_in[8];
    const float* Wa = (const float*)d_in[9];
    const float* ba = (const float*)d_in[10];

    const int N = in_sizes[0] / DIN;
    const int E = in_sizes[1];
    const int NB = (N + 1023) / 1024;

    float* out_f = (float*)d_out;
    float* edge_s_out = out_f;                        // chunk 0: [N,64]
    float* out_attn   = out_f + (size_t)N * DOUT;     // chunk 1: [N,64]
    float* h_out      = out_f + 2 * (size_t)N * DOUT; // chunk 2: [N,64]

    char* ws = (char*)d_ws;
    size_t o = 0;
    unsigned short* packed_bf = (unsigned short*)(ws + o); o += (size_t)N * 128 * 2;
    float* xd      = (float*)(ws + o); o += (size_t)N * DOUT * 4;
    float* alpha_s = (float*)(ws + o); o += (size_t)N * NHEAD * 4;
    float* alpha_d = (float*)(ws + o); o += (size_t)N * NHEAD * 4;
    int*   degi    = (int*)  (ws + o); o += (size_t)N * 4;
    int*   rp_raw  = (int*)  (ws + o); o += (size_t)(N + 1) * 4;
    int*   rank    = (int*)  (ws + o); o += (size_t)E * 4;
    int*   srcs    = (int*)  (ws + o); o += (size_t)E * 4;
    int*   bsum    = (int*)  (ws + o); o += (size_t)NB * 4;
    int*   boff    = (int*)  (ws + o); o += (size_t)NB * 4;
    int*   total   = (int*)  (ws + o); o += 64;
    short* wT      = (short*)(ws + o); o += (size_t)192 * 128 * 2;

    const int prep_n = (N > 192 * 128) ? N : 192 * 128;
    k_prep<<<(prep_n + 255) / 256, 256, 0, stream>>>(Ws, Wd, Wl, wT, degi, N);

    k_node_proj<<<(N + 15) / 16, 64, 0, stream>>>(x, wT, bs, bd, bl, Wa,
                                                  packed_bf, xd, alpha_s, alpha_d,
                                                  h_out, N);

    k_hist<<<((E + 3) / 4 + 255) / 256, 256, 0, stream>>>(dst, degi, rank, E);

    k_scan_block<<<NB, 1024, 0, stream>>>(degi, rp_raw, bsum, N);
    k_scan_bsum<<<1, 1024, 0, stream>>>(bsum, boff, total, NB);

    k_scatter<<<((E + 3) / 4 + 255) / 256, 256, 0, stream>>>(src, dst, rp_raw, boff,
                                                             rank, srcs, E);

    k_aggregate<<<(N + 3) / 4, 256, 0, stream>>>(rp_raw, boff, total, srcs,
                                                 packed_bf, xd,
                                                 alpha_s, alpha_d, Wa, ba,
                                                 edge_s_out, out_attn, N);
}